// Round 13
// baseline (72.957 us; speedup 1.0000x reference)
//
#include <hip/hip_runtime.h>
#include <hip/hip_bf16.h>
#include <math.h>

#define NB   64
#define NA   8732
#define NCLS 81
#define NTOT (NB * NA)   // 558848
#define NSLICE 64        // replication of level-1 histogram flush targets
#define K1BLK  4096      // K1 grid
#define SUMBLK 256       // SUM grid

// ---- workspace layout (bytes); [OFF_HISTA, OFF_SCAL+64) is memset to 0 ----
#define OFF_KEYS   0
#define OFF_HISTA  (NTOT * 4)                       // u32[NSLICE][256]
#define OFF_HIST2  (OFF_HISTA + NSLICE * 256 * 4)   // u32[4096]
#define OFF_SCAL   (OFF_HIST2 + 4096 * 4)           // 64 B
#define OFF_PBNP   (OFF_SCAL + 64)                  // u32[K1BLK]
#define OFF_PBPC   (OFF_PBNP + K1BLK * 4)           // f32[K1BLK]
#define OFF_PBNEG  (OFF_PBPC + K1BLK * 4)           // f32[SUMBLK]
#define OFF_PBLOC  (OFF_PBNEG + SUMBLK * 4)         // f32[SUMBLK]
#define OFF_PBBIN  (OFF_PBLOC + SUMBLK * 4)         // f32[SUMBLK]
#define ZERO_BYTES (NSLICE * 256 * 4 + 4096 * 4 + 64)
// scal: 0 num_pos(u32), 2 pos_conf(f32), 4 k(u32), 5 b1(u32), 6 cnt_above_l1(u32),
//       7 hi_edge(u32), 8 r(u32), 9 prefix20(u32), 10 bin_total(u32)

__device__ __forceinline__ unsigned f2k(float f) {
  unsigned u = __float_as_uint(f);
  return (u & 0x80000000u) ? ~u : (u | 0x80000000u);
}
__device__ __forceinline__ float k2fv(unsigned u) {
  return __uint_as_float((u & 0x80000000u) ? (u ^ 0x80000000u) : ~u);
}

// DPP neighbor fetch (VALU, no LDS pipe). ctrl must be a literal.
// 0xB1 = quad_perm [1,0,3,2] (xor1); 0x4E = quad_perm [2,3,0,1] (xor2);
// 0x141 = ROW_HALF_MIRROR (xor7 within 8); 0x140 = ROW_MIRROR (xor15 within 16).
// Sequence xor1,xor2,xor7,xor15 is a complete 16-lane sum butterfly.
#define DPPF(v, ctrl) \
  __int_as_float(__builtin_amdgcn_update_dpp(0, __float_as_int(v), ctrl, 0xF, 0xF, true))

// ---------------- Kernel 1: CE + keys + level-1 hist (3-deep pipeline, DPP reduce) ----
// 16 lanes per anchor. No ds_bpermute in the hot loop (R10 lesson: the serial
// shfl chain through the LDS pipe was the limiter candidate). No device-scope
// fences (R9 lesson: per-block __threadfence() = 13x regression).
__global__ __launch_bounds__(256, 8) void mbl_k1(
    const float* __restrict__ pred_conf, const int* __restrict__ gt_label,
    unsigned* __restrict__ keys, unsigned* __restrict__ hista,
    unsigned* __restrict__ pb_np, float* __restrict__ pb_pc) {
  __shared__ unsigned lhist[256];
  __shared__ float s_pc[4];
  __shared__ unsigned s_np[4];
  lhist[threadIdx.x] = 0u;
  __syncthreads();

  const int sub = threadIdx.x & 15;
  const int G   = gridDim.x << 4;                       // total groups = 65536
  const int base = (blockIdx.x << 4) + (threadIdx.x >> 4);

  float posconf = 0.f;
  unsigned npos = 0u;
  const char* cbase = (const char*)pred_conf;

  float a0, a1, a2, a3, a4, a80; int alab;
  float b0, b1v, b2v, b3, b4, b80; int blab;
  float c0, c1, c2, c3, c4, c80; int clab;

#define LOADS(p0, p1, p2, p3, p4, p80, plab, aa) do {                          \
    const char* _p = cbase + (unsigned)(aa) * 324u + (sub << 2);               \
    p0 = *(const float*)(_p);                                                  \
    p1 = *(const float*)(_p + 64);                                             \
    p2 = *(const float*)(_p + 128);                                            \
    p3 = *(const float*)(_p + 192);                                            \
    p4 = *(const float*)(_p + 256);                                            \
    p80 = (sub == 0) ? *(const float*)(cbase + (unsigned)(aa) * 324u + 320u)   \
                     : 0.f;                                                    \
    plab = gt_label[aa];                                                       \
  } while (0)

// e and pk reduced by the same DPP butterfly, chains interleaved for ILP.
#define COMPUTE(p0, p1, p2, p3, p4, p80, plab, aa) do {                        \
    float e = __expf(p0) + __expf(p1) + __expf(p2) + __expf(p3) + __expf(p4);  \
    if (sub == 0) e += __expf(p80);                                            \
    const int _d = (plab) - sub;                                               \
    float pk = (_d == 0)  ? p0 : (_d == 16) ? p1 : (_d == 32) ? p2             \
             : (_d == 48) ? p3 : (_d == 64) ? p4 : (_d == 80) ? p80 : 0.f;     \
    e += DPPF(e, 0xB1);   pk += DPPF(pk, 0xB1);                                \
    e += DPPF(e, 0x4E);   pk += DPPF(pk, 0x4E);                                \
    e += DPPF(e, 0x141);  pk += DPPF(pk, 0x141);                               \
    e += DPPF(e, 0x140);  pk += DPPF(pk, 0x140);                               \
    if (sub == 0) {                                                            \
      const float ce = __logf(e) - pk;                                         \
      if ((plab) > 0) {                                                        \
        npos += 1u; posconf += ce; keys[aa] = 0u;                              \
      } else {                                                                 \
        const unsigned _u = f2k(ce);                                           \
        keys[aa] = _u;                                                         \
        atomicAdd(&lhist[_u >> 24], 1u);                                       \
      }                                                                        \
    }                                                                          \
  } while (0)

  // 3-deep rotating pipeline with static register sets (rule #20)
  int i0 = base;
  bool v0 = i0 < NTOT;
  if (v0) {
    LOADS(a0, a1, a2, a3, a4, a80, alab, i0);
    int i1 = i0 + G;
    if (i1 < NTOT) LOADS(b0, b1v, b2v, b3, b4, b80, blab, i1);
    int ic = i1 + G;
    for (;;) {
      if (ic < NTOT) LOADS(c0, c1, c2, c3, c4, c80, clab, ic);
      COMPUTE(a0, a1, a2, a3, a4, a80, alab, i0);
      if (!(i1 < NTOT)) break;
      const int in = ic + G;
      if (in < NTOT) LOADS(a0, a1, a2, a3, a4, a80, alab, in);
      COMPUTE(b0, b1v, b2v, b3, b4, b80, blab, i1);
      if (!(ic < NTOT)) break;
      const int in2 = in + G;
      if (in2 < NTOT) LOADS(b0, b1v, b2v, b3, b4, b80, blab, in2);
      COMPUTE(c0, c1, c2, c3, c4, c80, clab, ic);
      if (!(in < NTOT)) break;
      i0 = in; i1 = in2; ic = in2 + G;
    }
  }
#undef LOADS
#undef COMPUTE

  // block-reduce scalars -> per-block partials (cold path; shfl ok here)
#pragma unroll
  for (int s = 1; s < 64; s <<= 1) {
    posconf += __shfl_xor(posconf, s);
    npos    += (unsigned)__shfl_xor((int)npos, s);
  }
  {
    const int wv = threadIdx.x >> 6;
    if ((threadIdx.x & 63) == 0) { s_pc[wv] = posconf; s_np[wv] = npos; }
  }
  __syncthreads();   // also orders lhist atomics before flush
  if (threadIdx.x == 0) {
    pb_pc[blockIdx.x] = s_pc[0] + s_pc[1] + s_pc[2] + s_pc[3];
    pb_np[blockIdx.x] = s_np[0] + s_np[1] + s_np[2] + s_np[3];
  }
  const unsigned hv = lhist[threadIdx.x];
  if (hv) atomicAdd(&hista[(blockIdx.x & (NSLICE - 1)) * 256 + threadIdx.x], hv);
}

// ---------------- sel1: reduce partials, pick level-1 bin ----------------
__global__ __launch_bounds__(256) void mbl_sel1(const unsigned* __restrict__ hista,
                                                const unsigned* __restrict__ pb_np,
                                                const float* __restrict__ pb_pc,
                                                unsigned* __restrict__ scal_u,
                                                float* __restrict__ scal_f) {
  __shared__ unsigned partial[256];
  __shared__ float q_pc[4];
  __shared__ unsigned q_np[4];
  __shared__ unsigned s_k;
  const int t = threadIdx.x;

  unsigned np = 0u; float pc = 0.f;
  for (int i = t; i < K1BLK; i += 256) { np += pb_np[i]; pc += pb_pc[i]; }
#pragma unroll
  for (int s = 1; s < 64; s <<= 1) {
    np += (unsigned)__shfl_xor((int)np, s);
    pc += __shfl_xor(pc, s);
  }
  if ((t & 63) == 0) { q_np[t >> 6] = np; q_pc[t >> 6] = pc; }
  __syncthreads();
  if (t == 0) {
    const unsigned tot = q_np[0] + q_np[1] + q_np[2] + q_np[3];
    scal_u[0] = tot;
    scal_f[2] = q_pc[0] + q_pc[1] + q_pc[2] + q_pc[3];
    const unsigned k = min(3u * tot, (unsigned)NTOT - tot);
    s_k = k; scal_u[4] = k;
    if (k == 0u) {   // defaults: nothing selected
      scal_u[7] = 0xFFFFFFFFu; scal_u[8] = 0u;
      scal_u[9] = 0xFFFFFFFFu; scal_u[10] = 1u;
    }
  }
  __syncthreads();
  const unsigned k = s_k;
  if (k == 0u) return;

  unsigned s = 0u;
  for (int sl = 0; sl < NSLICE; ++sl) s += hista[sl * 256 + t];
  unsigned val = s;
  partial[t] = val;
  __syncthreads();
  for (int off = 1; off < 256; off <<= 1) {
    const unsigned add = (t + off < 256) ? partial[t + off] : 0u;
    __syncthreads();
    val += add;
    partial[t] = val;
    __syncthreads();
  }
  const unsigned suf = val - s;   // count strictly above bin t
  if (suf < k && k <= suf + s) { scal_u[5] = (unsigned)t; scal_u[6] = suf; }
}

// ---------------- H2: 4096-bin refinement histogram (bits 23:12 within b1) ------------
__global__ __launch_bounds__(256) void mbl_h2(const unsigned* __restrict__ keys,
                                              unsigned* __restrict__ hist2,
                                              const unsigned* __restrict__ scal_u) {
  if (scal_u[4] == 0u) return;
  __shared__ unsigned lh[4096];
  for (int i = threadIdx.x; i < 4096; i += 256) lh[i] = 0u;
  __syncthreads();
  const unsigned b1 = scal_u[5];
  const int stride = gridDim.x * 256;
  for (int i = blockIdx.x * 256 + threadIdx.x; i < NTOT; i += stride) {
    const unsigned key = keys[i];
    if ((key >> 24) == b1) atomicAdd(&lh[(key >> 12) & 0xFFFu], 1u);
  }
  __syncthreads();
  for (int i = threadIdx.x; i < 4096; i += 256) {
    const unsigned v = lh[i];
    if (v) atomicAdd(&hist2[i], v);
  }
}

// ---------------- sel2: exact 20-bit threshold bin + tie count ----------------
__global__ __launch_bounds__(1024) void mbl_sel2(const unsigned* __restrict__ hist2,
                                                 unsigned* __restrict__ scal_u) {
  __shared__ unsigned partial[1024];
  if (scal_u[4] == 0u) return;
  const unsigned kt = scal_u[4] - scal_u[6];
  const unsigned b1 = scal_u[5];
  const int t = threadIdx.x;
  unsigned s = 0u;
#pragma unroll
  for (int i = 0; i < 4; ++i) s += hist2[t * 4 + i];
  unsigned val = s;
  partial[t] = val;
  __syncthreads();
  for (int off = 1; off < 1024; off <<= 1) {
    const unsigned add = (t + off < 1024) ? partial[t + off] : 0u;
    __syncthreads();
    val += add;
    partial[t] = val;
    __syncthreads();
  }
  const unsigned suf = val - s;
  if (suf < kt && kt <= suf + s) {
    unsigned c = suf;
    for (int b = 3; b >= 0; --b) {
      const unsigned h = hist2[t * 4 + b];
      if (c + h >= kt) {
        const unsigned bin = (unsigned)(t * 4 + b);
        scal_u[7] = (b1 << 24) | (bin << 12) | 0xFFFu;  // hi edge of threshold bin
        scal_u[9] = (b1 << 12) | bin;                    // 20-bit prefix of bin
        scal_u[8] = kt - c;                              // r keys taken from bin
        scal_u[10] = h;                                  // bin total count
        break;
      }
      c += h;
    }
  }
}

// ---------------- SUM: neg-CE above edge + in-bin sum + pos smooth-L1 ----------------
__global__ __launch_bounds__(256) void mbl_sum(
    const unsigned* __restrict__ keys, const int* __restrict__ gt_label,
    const float* __restrict__ pred_loc, const float* __restrict__ gt_loc,
    const unsigned* __restrict__ scal_u,
    float* __restrict__ pb_neg, float* __restrict__ pb_loc,
    float* __restrict__ pb_bin) {
  __shared__ float q_n[4], q_l[4], q_b[4];
  const unsigned T = scal_u[7];     // 0xFFFFFFFF when k==0
  const unsigned P20 = scal_u[9];   // never matches key>>12 when k==0
  float acc = 0.f, lacc = 0.f, bacc = 0.f;
  const int stride = gridDim.x * 256;
  for (int i = blockIdx.x * 256 + threadIdx.x; i < NTOT; i += stride) {
    const unsigned key = keys[i];
    if (key > T) acc += k2fv(key);
    else if ((key >> 12) == P20) bacc += k2fv(key);
    const int lb = gt_label[i];
    if (lb > 0) {   // ~3% of anchors: fetch loc data only where needed
      const float4 pl = ((const float4*)pred_loc)[i];
      const float4 gl = ((const float4*)gt_loc)[i];
      float d;
      d = fabsf(pl.x - gl.x); lacc += (d < 1.f) ? 0.5f * d * d : d - 0.5f;
      d = fabsf(pl.y - gl.y); lacc += (d < 1.f) ? 0.5f * d * d : d - 0.5f;
      d = fabsf(pl.z - gl.z); lacc += (d < 1.f) ? 0.5f * d * d : d - 0.5f;
      d = fabsf(pl.w - gl.w); lacc += (d < 1.f) ? 0.5f * d * d : d - 0.5f;
    }
  }
#pragma unroll
  for (int s = 1; s < 64; s <<= 1) {
    acc  += __shfl_xor(acc, s);
    lacc += __shfl_xor(lacc, s);
    bacc += __shfl_xor(bacc, s);
  }
  const int wv = threadIdx.x >> 6;
  if ((threadIdx.x & 63) == 0) { q_n[wv] = acc; q_l[wv] = lacc; q_b[wv] = bacc; }
  __syncthreads();
  if (threadIdx.x == 0) {
    pb_neg[blockIdx.x] = q_n[0] + q_n[1] + q_n[2] + q_n[3];
    pb_loc[blockIdx.x] = q_l[0] + q_l[1] + q_l[2] + q_l[3];
    pb_bin[blockIdx.x] = q_b[0] + q_b[1] + q_b[2] + q_b[3];
  }
}

// ---------------- Finalize ----------------
__global__ __launch_bounds__(256) void mbl_fin(const unsigned* __restrict__ scal_u,
                                               const float* __restrict__ scal_f,
                                               const float* __restrict__ pb_neg,
                                               const float* __restrict__ pb_loc,
                                               const float* __restrict__ pb_bin,
                                               float* __restrict__ out) {
  __shared__ float q_n[4], q_l[4], q_b[4];
  const int t = threadIdx.x;
  float n = pb_neg[t], l = pb_loc[t], b = pb_bin[t];
#pragma unroll
  for (int s = 1; s < 64; s <<= 1) {
    n += __shfl_xor(n, s);
    l += __shfl_xor(l, s);
    b += __shfl_xor(b, s);
  }
  const int wv = t >> 6;
  if ((t & 63) == 0) { q_n[wv] = n; q_l[wv] = l; q_b[wv] = b; }
  __syncthreads();
  if (t == 0) {
    float negsum = q_n[0] + q_n[1] + q_n[2] + q_n[3];
    const float locsum = q_l[0] + q_l[1] + q_l[2] + q_l[3];
    const float binsum = q_b[0] + q_b[1] + q_b[2] + q_b[3];
    const unsigned r = scal_u[8];
    if (r > 0u) negsum += (float)r * (binsum / (float)scal_u[10]);
    out[0] = (locsum + scal_f[2] + negsum) / (float)scal_u[0];
  }
}

extern "C" void kernel_launch(void* const* d_in, const int* in_sizes, int n_in,
                              void* d_out, int out_size, void* d_ws, size_t ws_size,
                              hipStream_t stream) {
  const float* pred_loc  = (const float*)d_in[0];
  const float* pred_conf = (const float*)d_in[1];
  const float* gt_loc    = (const float*)d_in[2];
  const int*   gt_label  = (const int*)d_in[3];
  float* out = (float*)d_out;

  char* ws = (char*)d_ws;
  unsigned* keys   = (unsigned*)(ws + OFF_KEYS);
  unsigned* hista  = (unsigned*)(ws + OFF_HISTA);
  unsigned* hist2  = (unsigned*)(ws + OFF_HIST2);
  unsigned* scal_u = (unsigned*)(ws + OFF_SCAL);
  float*    scal_f = (float*)(ws + OFF_SCAL);
  unsigned* pb_np  = (unsigned*)(ws + OFF_PBNP);
  float*    pb_pc  = (float*)(ws + OFF_PBPC);
  float*    pb_neg = (float*)(ws + OFF_PBNEG);
  float*    pb_loc = (float*)(ws + OFF_PBLOC);
  float*    pb_bin = (float*)(ws + OFF_PBBIN);

  // zero hista + hist2 + scalars (keys/partials fully overwritten every call)
  hipMemsetAsync(ws + OFF_HISTA, 0, ZERO_BYTES, stream);

  mbl_k1<<<K1BLK, 256, 0, stream>>>(pred_conf, gt_label, keys, hista, pb_np, pb_pc);
  mbl_sel1<<<1, 256, 0, stream>>>(hista, pb_np, pb_pc, scal_u, scal_f);
  mbl_h2<<<256, 256, 0, stream>>>(keys, hist2, scal_u);
  mbl_sel2<<<1, 1024, 0, stream>>>(hist2, scal_u);
  mbl_sum<<<SUMBLK, 256, 0, stream>>>(keys, gt_label, pred_loc, gt_loc, scal_u,
                                      pb_neg, pb_loc, pb_bin);
  mbl_fin<<<1, 256, 0, stream>>>(scal_u, scal_f, pb_neg, pb_loc, pb_bin, out);
}

// Round 14
// 69.977 us; speedup vs baseline: 1.0426x; 1.0426x over previous
//
#include <hip/hip_runtime.h>
#include <hip/hip_bf16.h>
#include <math.h>

#define NB   64
#define NA   8732
#define NCLS 81
#define NTOT (NB * NA)   // 558848
#define NTILE (NTOT / 16) // 34928 16-anchor tiles, exact
#define NSLICE 64        // replication of level-1 histogram flush targets
#define K1BLK  4096      // K1 grid (x4 waves = 16384 waves)
#define SUMBLK 256       // SUM grid

// ---- workspace layout (bytes); [OFF_HISTA, OFF_SCAL+64) is memset to 0 ----
#define OFF_KEYS   0
#define OFF_HISTA  (NTOT * 4)                       // u32[NSLICE][256]
#define OFF_HIST2  (OFF_HISTA + NSLICE * 256 * 4)   // u32[4096]
#define OFF_SCAL   (OFF_HIST2 + 4096 * 4)           // 64 B
#define OFF_PBNP   (OFF_SCAL + 64)                  // u32[K1BLK]
#define OFF_PBPC   (OFF_PBNP + K1BLK * 4)           // f32[K1BLK]
#define OFF_PBNEG  (OFF_PBPC + K1BLK * 4)           // f32[SUMBLK]
#define OFF_PBLOC  (OFF_PBNEG + SUMBLK * 4)         // f32[SUMBLK]
#define OFF_PBBIN  (OFF_PBLOC + SUMBLK * 4)         // f32[SUMBLK]
#define ZERO_BYTES (NSLICE * 256 * 4 + 4096 * 4 + 64)
// scal: 0 num_pos(u32), 2 pos_conf(f32), 4 k(u32), 5 b1(u32), 6 cnt_above_l1(u32),
//       7 hi_edge(u32), 8 r(u32), 9 prefix20(u32), 10 bin_total(u32)

__device__ __forceinline__ unsigned f2k(float f) {
  unsigned u = __float_as_uint(f);
  return (u & 0x80000000u) ? ~u : (u | 0x80000000u);
}
__device__ __forceinline__ float k2fv(unsigned u) {
  return __uint_as_float((u & 0x80000000u) ? (u ^ 0x80000000u) : ~u);
}

// DPP neighbor add (VALU, no LDS pipe). 0xB1 = quad_perm xor1; 0x4E = quad_perm xor2.
#define DPPF(v, ctrl) \
  __int_as_float(__builtin_amdgcn_update_dpp(0, __float_as_int(v), ctrl, 0xF, 0xF, true))

// ---------------- Kernel 1: tile-staged CE (float4 loads, per-wave LDS slice) --------
// One wave owns a 16-anchor tile (5184 B, 16B-aligned). 6 float4 loads/lane stage
// it to a private LDS slice (no barriers needed: single-wave scope). 4 lanes per
// anchor compute exp-sum from LDS (2-way bank alias = free), quad-DPP reduce.
// VMEM wave-instrs per 16 anchors: 28 (R10 scalar) -> 7.
__global__ __launch_bounds__(256, 7) void mbl_k1(
    const float* __restrict__ pred_conf, const int* __restrict__ gt_label,
    unsigned* __restrict__ keys, unsigned* __restrict__ hista,
    unsigned* __restrict__ pb_np, float* __restrict__ pb_pc) {
  __shared__ float srow[4][1312];   // 5248 B per wave slice (1296 used + pad)
  __shared__ unsigned lhist[256];
  __shared__ float s_pc[4];
  __shared__ unsigned s_np[4];
  lhist[threadIdx.x] = 0u;
  __syncthreads();

  const int lane = threadIdx.x & 63;
  const int wid  = threadIdx.x >> 6;
  const int gw   = (blockIdx.x << 2) + wid;    // global wave id, 16384 total
  const int l    = lane & 3;                   // lane within anchor-quad
  const int q    = lane >> 2;                  // anchor within tile (0..15)
  float* slice = srow[wid];
  float4* s4 = (float4*)slice;

  float posconf = 0.f;
  unsigned npos = 0u;

  for (int tile = gw; tile < NTILE; tile += K1BLK * 4) {
    const float4* src = (const float4*)pred_conf + (unsigned)tile * 324u;
    // ---- stage: 6 float4/lane, all in flight together (24 VGPR payload) ----
    const float4 r0 = src[lane];
    const float4 r1 = src[lane + 64];
    const float4 r2 = src[lane + 128];
    const float4 r3 = src[lane + 192];
    const float4 r4 = src[lane + 256];
    float4 r5;
    if (lane < 4) r5 = src[lane + 320];
    const int lab = gt_label[(tile << 4) + q];  // independent, rides same window

    s4[lane]       = r0;
    s4[lane + 64]  = r1;
    s4[lane + 128] = r2;
    s4[lane + 192] = r3;
    s4[lane + 256] = r4;
    if (lane < 4) s4[lane + 320] = r5;
    // single-wave slice: compiler orders ds_write -> ds_read via lgkmcnt deps

    // ---- per-anchor exp-sum: 4 lanes x ~20 floats, stride 4 ----
    const int rb = q * 81;
    float e = 0.f;
#pragma unroll
    for (int j = 0; j < 20; ++j) e += __expf(slice[rb + l + 4 * j]);
    if (l == 0) e += __expf(slice[rb + 80]);
    e += DPPF(e, 0xB1);   // xor1 within quad
    e += DPPF(e, 0x4E);   // xor2 within quad
    const float pick = slice[rb + lab];   // quad-broadcast read

    if (l == 0) {
      const float ce = __logf(e) - pick;
      const int a = (tile << 4) + q;
      if (lab > 0) {
        npos += 1u; posconf += ce; keys[a] = 0u;   // positives: below all negatives
      } else {
        const unsigned u = f2k(ce);
        keys[a] = u;
        atomicAdd(&lhist[u >> 24], 1u);
      }
    }
  }

  // ---- block-reduce scalars -> per-block partials (cold path) ----
#pragma unroll
  for (int s = 1; s < 64; s <<= 1) {
    posconf += __shfl_xor(posconf, s);
    npos    += (unsigned)__shfl_xor((int)npos, s);
  }
  if ((threadIdx.x & 63) == 0) { s_pc[wid] = posconf; s_np[wid] = npos; }
  __syncthreads();   // also orders lhist atomics before flush
  if (threadIdx.x == 0) {
    pb_pc[blockIdx.x] = s_pc[0] + s_pc[1] + s_pc[2] + s_pc[3];
    pb_np[blockIdx.x] = s_np[0] + s_np[1] + s_np[2] + s_np[3];
  }
  const unsigned hv = lhist[threadIdx.x];
  if (hv) atomicAdd(&hista[(blockIdx.x & (NSLICE - 1)) * 256 + threadIdx.x], hv);
}

// ---------------- sel1: reduce partials, pick level-1 bin ----------------
__global__ __launch_bounds__(256) void mbl_sel1(const unsigned* __restrict__ hista,
                                                const unsigned* __restrict__ pb_np,
                                                const float* __restrict__ pb_pc,
                                                unsigned* __restrict__ scal_u,
                                                float* __restrict__ scal_f) {
  __shared__ unsigned partial[256];
  __shared__ float q_pc[4];
  __shared__ unsigned q_np[4];
  __shared__ unsigned s_k;
  const int t = threadIdx.x;

  unsigned np = 0u; float pc = 0.f;
  for (int i = t; i < K1BLK; i += 256) { np += pb_np[i]; pc += pb_pc[i]; }
#pragma unroll
  for (int s = 1; s < 64; s <<= 1) {
    np += (unsigned)__shfl_xor((int)np, s);
    pc += __shfl_xor(pc, s);
  }
  if ((t & 63) == 0) { q_np[t >> 6] = np; q_pc[t >> 6] = pc; }
  __syncthreads();
  if (t == 0) {
    const unsigned tot = q_np[0] + q_np[1] + q_np[2] + q_np[3];
    scal_u[0] = tot;
    scal_f[2] = q_pc[0] + q_pc[1] + q_pc[2] + q_pc[3];
    const unsigned k = min(3u * tot, (unsigned)NTOT - tot);
    s_k = k; scal_u[4] = k;
    if (k == 0u) {   // defaults: nothing selected
      scal_u[7] = 0xFFFFFFFFu; scal_u[8] = 0u;
      scal_u[9] = 0xFFFFFFFFu; scal_u[10] = 1u;
    }
  }
  __syncthreads();
  const unsigned k = s_k;
  if (k == 0u) return;

  unsigned s = 0u;
  for (int sl = 0; sl < NSLICE; ++sl) s += hista[sl * 256 + t];
  unsigned val = s;
  partial[t] = val;
  __syncthreads();
  for (int off = 1; off < 256; off <<= 1) {
    const unsigned add = (t + off < 256) ? partial[t + off] : 0u;
    __syncthreads();
    val += add;
    partial[t] = val;
    __syncthreads();
  }
  const unsigned suf = val - s;   // count strictly above bin t
  if (suf < k && k <= suf + s) { scal_u[5] = (unsigned)t; scal_u[6] = suf; }
}

// ---------------- H2: 4096-bin refinement histogram (bits 23:12 within b1) ------------
__global__ __launch_bounds__(256) void mbl_h2(const unsigned* __restrict__ keys,
                                              unsigned* __restrict__ hist2,
                                              const unsigned* __restrict__ scal_u) {
  if (scal_u[4] == 0u) return;
  __shared__ unsigned lh[4096];
  for (int i = threadIdx.x; i < 4096; i += 256) lh[i] = 0u;
  __syncthreads();
  const unsigned b1 = scal_u[5];
  const int stride = gridDim.x * 256;
  for (int i = blockIdx.x * 256 + threadIdx.x; i < NTOT; i += stride) {
    const unsigned key = keys[i];
    if ((key >> 24) == b1) atomicAdd(&lh[(key >> 12) & 0xFFFu], 1u);
  }
  __syncthreads();
  for (int i = threadIdx.x; i < 4096; i += 256) {
    const unsigned v = lh[i];
    if (v) atomicAdd(&hist2[i], v);
  }
}

// ---------------- sel2: exact 20-bit threshold bin + tie count ----------------
__global__ __launch_bounds__(1024) void mbl_sel2(const unsigned* __restrict__ hist2,
                                                 unsigned* __restrict__ scal_u) {
  __shared__ unsigned partial[1024];
  if (scal_u[4] == 0u) return;
  const unsigned kt = scal_u[4] - scal_u[6];
  const unsigned b1 = scal_u[5];
  const int t = threadIdx.x;
  unsigned s = 0u;
#pragma unroll
  for (int i = 0; i < 4; ++i) s += hist2[t * 4 + i];
  unsigned val = s;
  partial[t] = val;
  __syncthreads();
  for (int off = 1; off < 1024; off <<= 1) {
    const unsigned add = (t + off < 1024) ? partial[t + off] : 0u;
    __syncthreads();
    val += add;
    partial[t] = val;
    __syncthreads();
  }
  const unsigned suf = val - s;
  if (suf < kt && kt <= suf + s) {
    unsigned c = suf;
    for (int b = 3; b >= 0; --b) {
      const unsigned h = hist2[t * 4 + b];
      if (c + h >= kt) {
        const unsigned bin = (unsigned)(t * 4 + b);
        scal_u[7] = (b1 << 24) | (bin << 12) | 0xFFFu;  // hi edge of threshold bin
        scal_u[9] = (b1 << 12) | bin;                    // 20-bit prefix of bin
        scal_u[8] = kt - c;                              // r keys taken from bin
        scal_u[10] = h;                                  // bin total count
        break;
      }
      c += h;
    }
  }
}

// ---------------- SUM: neg-CE above edge + in-bin sum + pos smooth-L1 ----------------
__global__ __launch_bounds__(256) void mbl_sum(
    const unsigned* __restrict__ keys, const int* __restrict__ gt_label,
    const float* __restrict__ pred_loc, const float* __restrict__ gt_loc,
    const unsigned* __restrict__ scal_u,
    float* __restrict__ pb_neg, float* __restrict__ pb_loc,
    float* __restrict__ pb_bin) {
  __shared__ float q_n[4], q_l[4], q_b[4];
  const unsigned T = scal_u[7];     // 0xFFFFFFFF when k==0
  const unsigned P20 = scal_u[9];   // never matches key>>12 when k==0
  float acc = 0.f, lacc = 0.f, bacc = 0.f;
  const int stride = gridDim.x * 256;
  for (int i = blockIdx.x * 256 + threadIdx.x; i < NTOT; i += stride) {
    const unsigned key = keys[i];
    if (key > T) acc += k2fv(key);
    else if ((key >> 12) == P20) bacc += k2fv(key);
    const int lb = gt_label[i];
    if (lb > 0) {   // ~3% of anchors: fetch loc data only where needed
      const float4 pl = ((const float4*)pred_loc)[i];
      const float4 gl = ((const float4*)gt_loc)[i];
      float d;
      d = fabsf(pl.x - gl.x); lacc += (d < 1.f) ? 0.5f * d * d : d - 0.5f;
      d = fabsf(pl.y - gl.y); lacc += (d < 1.f) ? 0.5f * d * d : d - 0.5f;
      d = fabsf(pl.z - gl.z); lacc += (d < 1.f) ? 0.5f * d * d : d - 0.5f;
      d = fabsf(pl.w - gl.w); lacc += (d < 1.f) ? 0.5f * d * d : d - 0.5f;
    }
  }
#pragma unroll
  for (int s = 1; s < 64; s <<= 1) {
    acc  += __shfl_xor(acc, s);
    lacc += __shfl_xor(lacc, s);
    bacc += __shfl_xor(bacc, s);
  }
  const int wv = threadIdx.x >> 6;
  if ((threadIdx.x & 63) == 0) { q_n[wv] = acc; q_l[wv] = lacc; q_b[wv] = bacc; }
  __syncthreads();
  if (threadIdx.x == 0) {
    pb_neg[blockIdx.x] = q_n[0] + q_n[1] + q_n[2] + q_n[3];
    pb_loc[blockIdx.x] = q_l[0] + q_l[1] + q_l[2] + q_l[3];
    pb_bin[blockIdx.x] = q_b[0] + q_b[1] + q_b[2] + q_b[3];
  }
}

// ---------------- Finalize ----------------
__global__ __launch_bounds__(256) void mbl_fin(const unsigned* __restrict__ scal_u,
                                               const float* __restrict__ scal_f,
                                               const float* __restrict__ pb_neg,
                                               const float* __restrict__ pb_loc,
                                               const float* __restrict__ pb_bin,
                                               float* __restrict__ out) {
  __shared__ float q_n[4], q_l[4], q_b[4];
  const int t = threadIdx.x;
  float n = pb_neg[t], l = pb_loc[t], b = pb_bin[t];
#pragma unroll
  for (int s = 1; s < 64; s <<= 1) {
    n += __shfl_xor(n, s);
    l += __shfl_xor(l, s);
    b += __shfl_xor(b, s);
  }
  const int wv = t >> 6;
  if ((t & 63) == 0) { q_n[wv] = n; q_l[wv] = l; q_b[wv] = b; }
  __syncthreads();
  if (t == 0) {
    float negsum = q_n[0] + q_n[1] + q_n[2] + q_n[3];
    const float locsum = q_l[0] + q_l[1] + q_l[2] + q_l[3];
    const float binsum = q_b[0] + q_b[1] + q_b[2] + q_b[3];
    const unsigned r = scal_u[8];
    if (r > 0u) negsum += (float)r * (binsum / (float)scal_u[10]);
    out[0] = (locsum + scal_f[2] + negsum) / (float)scal_u[0];
  }
}

extern "C" void kernel_launch(void* const* d_in, const int* in_sizes, int n_in,
                              void* d_out, int out_size, void* d_ws, size_t ws_size,
                              hipStream_t stream) {
  const float* pred_loc  = (const float*)d_in[0];
  const float* pred_conf = (const float*)d_in[1];
  const float* gt_loc    = (const float*)d_in[2];
  const int*   gt_label  = (const int*)d_in[3];
  float* out = (float*)d_out;

  char* ws = (char*)d_ws;
  unsigned* keys   = (unsigned*)(ws + OFF_KEYS);
  unsigned* hista  = (unsigned*)(ws + OFF_HISTA);
  unsigned* hist2  = (unsigned*)(ws + OFF_HIST2);
  unsigned* scal_u = (unsigned*)(ws + OFF_SCAL);
  float*    scal_f = (float*)(ws + OFF_SCAL);
  unsigned* pb_np  = (unsigned*)(ws + OFF_PBNP);
  float*    pb_pc  = (float*)(ws + OFF_PBPC);
  float*    pb_neg = (float*)(ws + OFF_PBNEG);
  float*    pb_loc = (float*)(ws + OFF_PBLOC);
  float*    pb_bin = (float*)(ws + OFF_PBBIN);

  // zero hista + hist2 + scalars (keys/partials fully overwritten every call)
  hipMemsetAsync(ws + OFF_HISTA, 0, ZERO_BYTES, stream);

  mbl_k1<<<K1BLK, 256, 0, stream>>>(pred_conf, gt_label, keys, hista, pb_np, pb_pc);
  mbl_sel1<<<1, 256, 0, stream>>>(hista, pb_np, pb_pc, scal_u, scal_f);
  mbl_h2<<<256, 256, 0, stream>>>(keys, hist2, scal_u);
  mbl_sel2<<<1, 1024, 0, stream>>>(hist2, scal_u);
  mbl_sum<<<SUMBLK, 256, 0, stream>>>(keys, gt_label, pred_loc, gt_loc, scal_u,
                                      pb_neg, pb_loc, pb_bin);
  mbl_fin<<<1, 256, 0, stream>>>(scal_u, scal_f, pb_neg, pb_loc, pb_bin, out);
}